// Round 7
// baseline (882.644 us; speedup 1.0000x reference)
//
#include <hip/hip_runtime.h>
#include <hip/hip_bf16.h>

// ---------------------------------------------------------------------------
// LeViT subsample attention (round 6).
//   1. prep: x -> xb (bf16), xbT (bf16 transposed), xqT (gathered transposed)
//   2. Sx = xbT @ xbT^T via split-K MFMA -> ps -> reduce -> sx (f32) -> bf16
//      cs = rowsum(xbT/xqT)
//   3. T = Sx @ W (MFMA); bnfinal -> analytic BN coefficients a,b
//   4. Kbuf = BN(x@Wk); Vt = BN(x@Wv) transposed; Qn (gathered rows)
//   5. attn_mfma: single-pass no-max softmax; XCD pair-swizzle (V L2 share),
//      V-register prefetch 1 tile ahead, XOR-swizzled LDS -> hswish(O) bf16
//   6. out = O @ Wout^T -> f32
// ---------------------------------------------------------------------------

static constexpr int M1 = 25088, N1 = 3840, Kc = 384;
static constexpr int M2 = 6272, Dq = 768, OUTD = 512;
static constexpr int CH1 = 14, CH2 = 7;

static constexpr size_t OFF_K    = 0;            // bf16 25088x768 (late)
static constexpr size_t OFF_XBT  = 0;            // bf16 384x25088 (early)
static constexpr size_t OFF_XQT  = 19267584;     // bf16 384x6272
static constexpr size_t OFF_T1   = 24084480;     // f32 384x3840
static constexpr size_t OFF_T2   = 29982720;     // f32 384x768
static constexpr size_t OFF_SXB1 = 31162368;     // bf16 384x384
static constexpr size_t OFF_SXB2 = 31457280;     // ends 31752192 < OFF_VT
static constexpr size_t OFF_VT   = 38535168;     // bf16 (32*12*256)x784
static constexpr size_t OFF_QN   = 192675840;    // bf16 6272x768
static constexpr size_t OFF_O    = 202309632;    // bf16 6272x3072 (xb early)
static constexpr size_t OFF_XB   = OFF_O;
static constexpr size_t OFF_PS1  = 240844800;    // f32 14x384x384 (early)
static constexpr size_t OFF_WQKVT= 240844800;    // bf16 3840x384 (over PS1)
static constexpr size_t OFF_WQT  = 243793920;    // bf16 768x384
static constexpr size_t OFF_WOUTT= 244383744;    // bf16 512x3072
static constexpr size_t OFF_PS2  = 249123840;    // f32 7x384x384
static constexpr size_t OFF_SX1  = 253263360;
static constexpr size_t OFF_CS1  = 253853184;
static constexpr size_t OFF_SX2  = 253854720;
static constexpr size_t OFF_CS2  = 254444544;
static constexpr size_t OFF_A1   = 254446080;
static constexpr size_t OFF_B1   = 254461440;
static constexpr size_t OFF_A2   = 254476800;
static constexpr size_t OFF_B2   = 254479872;
static constexpr size_t WS_TOTAL = 254482944;

typedef __attribute__((ext_vector_type(8))) short bf16x8;
typedef __attribute__((ext_vector_type(4))) float f32x4;

static __device__ __forceinline__ f32x4 mfma16(bf16x8 a, bf16x8 b, f32x4 c) {
  return __builtin_amdgcn_mfma_f32_16x16x32_bf16(a, b, c, 0, 0, 0);
}

__device__ __forceinline__ void gload_lds16(const void* g, void* l) {
  __builtin_amdgcn_global_load_lds(
      (const __attribute__((address_space(1))) unsigned int*)g,
      (__attribute__((address_space(3))) unsigned int*)l, 16, 0, 0);
}

__device__ __forceinline__ float hswish(float x) {
  float t = fminf(fmaxf(x + 3.0f, 0.0f), 6.0f);
  return x * t * (1.0f / 6.0f);
}

// --------------------------- prep kernels ----------------------------------
__global__ __launch_bounds__(256) void convert_bf16(
    const float* __restrict__ in, unsigned short* __restrict__ out, long n8) {
  long i = (long)blockIdx.x * 256 + threadIdx.x;
  if (i >= n8) return;
  float4 a = ((const float4*)in)[i * 2];
  float4 b = ((const float4*)in)[i * 2 + 1];
  union { uint4 u; __hip_bfloat16 h[8]; } pk;
  pk.h[0] = __float2bfloat16(a.x); pk.h[1] = __float2bfloat16(a.y);
  pk.h[2] = __float2bfloat16(a.z); pk.h[3] = __float2bfloat16(a.w);
  pk.h[4] = __float2bfloat16(b.x); pk.h[5] = __float2bfloat16(b.y);
  pk.h[6] = __float2bfloat16(b.z); pk.h[7] = __float2bfloat16(b.w);
  ((uint4*)out)[i] = pk.u;
}

// in[R][C] f32 -> out[C][R] bf16; grid (C/32, R/32)
__global__ __launch_bounds__(256) void transpose_bf16(
    const float* __restrict__ in, unsigned short* __restrict__ out, int R, int C) {
  __shared__ float t[32][33];
  const int c0 = blockIdx.x * 32, r0 = blockIdx.y * 32;
  const int x = threadIdx.x & 31, y = threadIdx.x >> 5;
  #pragma unroll
  for (int i = y; i < 32; i += 8) t[i][x] = in[(long)(r0 + i) * C + c0 + x];
  __syncthreads();
  #pragma unroll
  for (int i = y; i < 32; i += 8) {
    __hip_bfloat16 v = __float2bfloat16(t[x][i]);
    out[(long)(c0 + i) * R + r0 + x] = *(unsigned short*)&v;
  }
}

// x (::2,::2 gathered rows) -> xqT[384][6272] bf16; grid (12, 196)
__global__ __launch_bounds__(256) void transpose_gather_bf16(
    const float* __restrict__ in, unsigned short* __restrict__ out) {
  __shared__ float t[32][33];
  const int c0 = blockIdx.x * 32, r0 = blockIdx.y * 32;
  const int x = threadIdx.x & 31, y = threadIdx.x >> 5;
  #pragma unroll
  for (int i = y; i < 32; i += 8) {
    int m2 = r0 + i;
    int bb = m2 / 196, tt = m2 - bb * 196;
    int h2 = tt / 14, w2 = tt - h2 * 14;
    long grow = (long)(bb * 784 + h2 * 56 + w2 * 2);
    t[i][x] = in[grow * 384 + c0 + x];
  }
  __syncthreads();
  #pragma unroll
  for (int i = y; i < 32; i += 8) {
    __hip_bfloat16 v = __float2bfloat16(t[x][i]);
    out[(long)(c0 + i) * 6272 + r0 + x] = *(unsigned short*)&v;
  }
}

// per-row sum of bf16 matrix row (grid = nrows)
__global__ __launch_bounds__(256) void rowsum_bf16(
    const unsigned short* __restrict__ src, float* __restrict__ dst, int ncols) {
  const long base = (long)blockIdx.x * ncols;
  float s = 0.f;
  for (int c = threadIdx.x * 8; c < ncols; c += 2048) {
    bf16x8 v = *(const bf16x8*)(src + base + c);
    #pragma unroll
    for (int j = 0; j < 8; ++j)
      s += __uint_as_float(((unsigned)(unsigned short)v[j]) << 16);
  }
  __shared__ float red[256];
  red[threadIdx.x] = s;
  __syncthreads();
  for (int st = 128; st > 0; st >>= 1) {
    if (threadIdx.x < st) red[threadIdx.x] += red[threadIdx.x + st];
    __syncthreads();
  }
  if (threadIdx.x == 0) dst[blockIdx.x] = red[0];
}

__global__ __launch_bounds__(256) void reduce_chunks(
    const float* __restrict__ src, float* __restrict__ dst, int nelem, int nchunks) {
  int i = blockIdx.x * 256 + threadIdx.x;
  if (i >= nelem) return;
  float s = 0.f;
  for (int c = 0; c < nchunks; ++c) s += src[(long)c * nelem + i];
  dst[i] = s;
}

// --------------------------- BN finalize -----------------------------------
__global__ __launch_bounds__(256) void bnfinal(
    const float* __restrict__ W, const float* __restrict__ T, const float* __restrict__ cs,
    const float* __restrict__ scale, float* __restrict__ a, float* __restrict__ b,
    int N, float invM) {
  const int j = blockIdx.x * 64 + (threadIdx.x & 63);
  const int rq = threadIdx.x >> 6;
  float yy = 0.f, mu = 0.f;
  for (int k = rq * 96; k < rq * 96 + 96; ++k) {
    float w = W[(long)k * N + j];
    yy += w * T[(long)k * N + j];
    mu += cs[k] * w;
  }
  __shared__ float r1[256], r2[256];
  r1[threadIdx.x] = yy; r2[threadIdx.x] = mu;
  __syncthreads();
  if (threadIdx.x < 64) {
    int t = threadIdx.x;
    yy = r1[t] + r1[t + 64] + r1[t + 128] + r1[t + 192];
    mu = r2[t] + r2[t + 64] + r2[t + 128] + r2[t + 192];
    float mean = mu * invM;
    float var = yy * invM - mean * mean;
    float ai = rsqrtf(var + 1e-5f) * scale[j];
    a[j] = ai;
    b[j] = -mean * ai;
  }
}

// ---------------------------------------------------------------------------
// split-K MFMA X @ X^T: Cpart[z] = X[:, zK..zK+Kchunk] times itself^T.
// X is [384][Kfull] bf16. grid (3, 3, chunks).
// ---------------------------------------------------------------------------
__global__ __launch_bounds__(256) void sx_mfma(
    const unsigned short* __restrict__ X, float* __restrict__ Cpart,
    int Kfull, int Kchunk) {
  __shared__ __align__(16) char As[16384];
  __shared__ __align__(16) char Bs[16384];
  const int tid = threadIdx.x;
  const int lane = tid & 63;
  const int wv = tid >> 6;
  const int wm = (wv >> 1) * 64, wn = (wv & 1) * 64;
  const int m0 = blockIdx.y * 128, n0 = blockIdx.x * 128;
  const int cl = lane & 15, kg = lane >> 4;
  const int srow = tid >> 3;
  const int swz = ((tid & 7) * 16) ^ ((srow & 7) << 4);
  const int ldsb = wv * 1024;
  const long zbase = (long)blockIdx.z * Kchunk;

  long arow[4], brow[4];
  #pragma unroll
  for (int is = 0; is < 4; ++is) {
    arow[is] = (long)(m0 + is * 32 + srow) * Kfull + zbase;
    brow[is] = (long)(n0 + is * 32 + srow) * Kfull + zbase;
  }

  f32x4 acc[4][4];
  const f32x4 zf = {0.f, 0.f, 0.f, 0.f};
  #pragma unroll
  for (int i = 0; i < 4; ++i)
    #pragma unroll
    for (int j = 0; j < 4; ++j) acc[i][j] = zf;

  for (int k0 = 0; k0 < Kchunk; k0 += 64) {
    #pragma unroll
    for (int is = 0; is < 4; ++is) {
      gload_lds16((const char*)X + (arow[is] + k0) * 2 + swz, As + is * 4096 + ldsb);
      gload_lds16((const char*)X + (brow[is] + k0) * 2 + swz, Bs + is * 4096 + ldsb);
    }
    __syncthreads();
    bf16x8 afr[4][2], bfr[4][2];
    #pragma unroll
    for (int t = 0; t < 4; ++t) {
      const int ar = wm + t * 16 + cl;
      const int br = wn + t * 16 + cl;
      const int sa = (ar & 7) << 4, sb = (br & 7) << 4;
      afr[t][0] = *(const bf16x8*)(As + ar * 128 + ((kg * 16) ^ sa));
      afr[t][1] = *(const bf16x8*)(As + ar * 128 + ((64 + kg * 16) ^ sa));
      bfr[t][0] = *(const bf16x8*)(Bs + br * 128 + ((kg * 16) ^ sb));
      bfr[t][1] = *(const bf16x8*)(Bs + br * 128 + ((64 + kg * 16) ^ sb));
    }
    #pragma unroll
    for (int mt = 0; mt < 4; ++mt)
      #pragma unroll
      for (int nt = 0; nt < 4; ++nt) {
        acc[mt][nt] = mfma16(bfr[nt][0], afr[mt][0], acc[mt][nt]);
        acc[mt][nt] = mfma16(bfr[nt][1], afr[mt][1], acc[mt][nt]);
      }
    __syncthreads();
  }

  float* Cp = Cpart + (long)blockIdx.z * 384 * 384;
  #pragma unroll
  for (int mt = 0; mt < 4; ++mt) {
    const int gm = m0 + wm + mt * 16 + cl;
    #pragma unroll
    for (int nt = 0; nt < 4; ++nt) {
      const int gn = n0 + wn + nt * 16 + kg * 4;
      *(float4*)(Cp + (long)gm * 384 + gn) =
          make_float4(acc[mt][nt][0], acc[mt][nt][1], acc[mt][nt][2], acc[mt][nt][3]);
    }
  }
}

// ---------------------------------------------------------------------------
// bf16 MFMA GEMM: C = A[M,K] @ Bt[N,K]^T.  (unchanged from round 5)
// ---------------------------------------------------------------------------
template<int AMODE, int EPI>
__global__ __launch_bounds__(256) void gemm_mfma(
    const unsigned short* __restrict__ A, const unsigned short* __restrict__ Bt,
    void* __restrict__ Cout, const float* __restrict__ ea, const float* __restrict__ eb,
    int N, int K) {
  __shared__ __align__(16) char As[16384];
  __shared__ __align__(16) char Bs[16384];
  const int tid = threadIdx.x;
  const int lane = tid & 63;
  const int wv = tid >> 6;
  const int wm = (wv >> 1) * 64, wn = (wv & 1) * 64;
  const int m0 = blockIdx.y * 128, n0 = blockIdx.x * 128;
  const int cl = lane & 15, kg = lane >> 4;

  const int srow = tid >> 3;
  const int swz = ((tid & 7) * 16) ^ ((srow & 7) << 4);
  const int ldsb = wv * 1024;

  long arow[4], brow[4];
  #pragma unroll
  for (int is = 0; is < 4; ++is) {
    int gm = m0 + is * 32 + srow;
    long grow;
    if constexpr (AMODE == 1) {
      int bb = gm / 196, t = gm - bb * 196;
      int h2 = t / 14, w2 = t - h2 * 14;
      grow = (long)(bb * 784 + h2 * 56 + w2 * 2);
    } else {
      grow = gm;
    }
    arow[is] = grow * (long)K;
    brow[is] = (long)(n0 + is * 32 + srow) * (long)K;
  }

  f32x4 acc[4][4];
  const f32x4 zf = {0.f, 0.f, 0.f, 0.f};
  #pragma unroll
  for (int i = 0; i < 4; ++i)
    #pragma unroll
    for (int j = 0; j < 4; ++j) acc[i][j] = zf;

  for (int k0 = 0; k0 < K; k0 += 64) {
    #pragma unroll
    for (int is = 0; is < 4; ++is) {
      gload_lds16((const char*)A  + (arow[is] + k0) * 2 + swz, As + is * 4096 + ldsb);
      gload_lds16((const char*)Bt + (brow[is] + k0) * 2 + swz, Bs + is * 4096 + ldsb);
    }
    __syncthreads();
    bf16x8 afr[4][2], bfr[4][2];
    #pragma unroll
    for (int t = 0; t < 4; ++t) {
      const int ar = wm + t * 16 + cl;
      const int br = wn + t * 16 + cl;
      const int sa = (ar & 7) << 4, sb = (br & 7) << 4;
      afr[t][0] = *(const bf16x8*)(As + ar * 128 + ((kg * 16) ^ sa));
      afr[t][1] = *(const bf16x8*)(As + ar * 128 + ((64 + kg * 16) ^ sa));
      bfr[t][0] = *(const bf16x8*)(Bs + br * 128 + ((kg * 16) ^ sb));
      bfr[t][1] = *(const bf16x8*)(Bs + br * 128 + ((64 + kg * 16) ^ sb));
    }
    #pragma unroll
    for (int mt = 0; mt < 4; ++mt)
      #pragma unroll
      for (int nt = 0; nt < 4; ++nt) {
        if constexpr (EPI == 2) {
          acc[mt][nt] = mfma16(afr[mt][0], bfr[nt][0], acc[mt][nt]);
          acc[mt][nt] = mfma16(afr[mt][1], bfr[nt][1], acc[mt][nt]);
        } else {
          acc[mt][nt] = mfma16(bfr[nt][0], afr[mt][0], acc[mt][nt]);
          acc[mt][nt] = mfma16(bfr[nt][1], afr[mt][1], acc[mt][nt]);
        }
      }
    __syncthreads();
  }

  #pragma unroll
  for (int mt = 0; mt < 4; ++mt) {
    #pragma unroll
    for (int nt = 0; nt < 4; ++nt) {
      if constexpr (EPI == 2) {
        const int gm0 = m0 + wm + mt * 16 + kg * 4;
        const int gn = n0 + wn + nt * 16 + cl;
        const int bb = gm0 / 784, kk = gm0 - bb * 784;
        const int hh = gn >> 8, dvl = gn & 255;
        const float av = ea[gn], bv = eb[gn];
        union { ushort4 u; __hip_bfloat16 h[4]; } pk;
        pk.h[0] = __float2bfloat16(acc[mt][nt][0] * av + bv);
        pk.h[1] = __float2bfloat16(acc[mt][nt][1] * av + bv);
        pk.h[2] = __float2bfloat16(acc[mt][nt][2] * av + bv);
        pk.h[3] = __float2bfloat16(acc[mt][nt][3] * av + bv);
        *(ushort4*)((unsigned short*)Cout +
                    ((long)(bb * 12 + hh) * 256 + dvl) * 784 + kk) = pk.u;
      } else {
        const int gm = m0 + wm + mt * 16 + cl;
        const int gn = n0 + wn + nt * 16 + kg * 4;
        if constexpr (EPI == 1) {
          float4 a4 = *(const float4*)(ea + gn);
          float4 b4 = *(const float4*)(eb + gn);
          union { ushort4 u; __hip_bfloat16 h[4]; } pk;
          pk.h[0] = __float2bfloat16(acc[mt][nt][0] * a4.x + b4.x);
          pk.h[1] = __float2bfloat16(acc[mt][nt][1] * a4.y + b4.y);
          pk.h[2] = __float2bfloat16(acc[mt][nt][2] * a4.z + b4.z);
          pk.h[3] = __float2bfloat16(acc[mt][nt][3] * a4.w + b4.w);
          *(ushort4*)((unsigned short*)Cout + (long)gm * N + gn) = pk.u;
        } else {
          *(float4*)((float*)Cout + (long)gm * N + gn) =
              make_float4(acc[mt][nt][0], acc[mt][nt][1], acc[mt][nt][2], acc[mt][nt][3]);
        }
      }
    }
  }
}

// ---------------------------------------------------------------------------
// Single-pass MFMA flash attention (no max; scores bounded).
// XCD pair-swizzle: physical blocks p and p+384 handle qt=0/1 of the same
// (b,h) and land on the same XCD (p%8) -> V shared in L2 (all 768 resident).
// V fragments prefetched 1 k-tile ahead into registers (ping-pong A/B).
// Qs/Ks/pPs XOR-swizzled (byte ^= (row&7)<<4) to cut b128 bank conflicts.
// ---------------------------------------------------------------------------
#define SWZB(row, bcol) ((bcol) ^ (((row) & 7) << 4))

#define LOAD_VF(KT, V0, V1, V2, V3) { \
    const int kvo_ = (KT) * 64 + kb; \
    V0 = *(const bf16x8*)(vt + vr0 + kvo_); \
    V1 = *(const bf16x8*)(vt + vr0 + kvo_ + 32); \
    V2 = *(const bf16x8*)(vt + vr1 + kvo_); \
    V3 = *(const bf16x8*)(vt + vr1 + kvo_ + 32); }

#define ATTN_STEP(KT, CUR, NXT, VC0, VC1, VC2, VC3, VN0, VN1, VN2, VN3) { \
    const int k0_ = (KT) * 64; \
    if ((KT) < 12) { \
      int kk_ = tid >> 3, d8_ = tid & 7; \
      bf16x8 v_ = zero8; \
      if (k0_ + 64 + kk_ < 784) \
        v_ = *(const bf16x8*)(kbuf + ((long)b * 784 + k0_ + 64 + kk_) * 768 + h * 64 + d8_ * 8); \
      *(bf16x8*)((char*)&Ks[NXT][kk_][0] + SWZB(kk_, d8_ * 16)) = v_; \
    } \
    if ((KT) + 1 < 13) { LOAD_VF((KT) + 1, VN0, VN1, VN2, VN3); } \
    _Pragma("unroll") \
    for (int i_ = 0; i_ < 4; ++i_) { \
      int mt_ = mt0 + 2 * i_; \
      if (mt_ >= 7) break; \
      const int qrow_ = mt_ * 16 + cl; \
      const int krow_ = snt * 16 + cl; \
      bf16x8 q0_ = *(const bf16x8*)((const char*)&Qs[qrow_][0] + SWZB(qrow_, kg * 16)); \
      bf16x8 q1_ = *(const bf16x8*)((const char*)&Qs[qrow_][0] + SWZB(qrow_, 64 + kg * 16)); \
      bf16x8 k0f_ = *(const bf16x8*)((const char*)&Ks[CUR][krow_][0] + SWZB(krow_, kg * 16)); \
      bf16x8 k1f_ = *(const bf16x8*)((const char*)&Ks[CUR][krow_][0] + SWZB(krow_, 64 + kg * 16)); \
      f32x4 s_ = mfma16(k1f_, q1_, mfma16(k0f_, q0_, zerof)); \
      const int key0_ = k0_ + snt * 16 + kg * 4; \
      const bool ok_ = (qrow_ < valid) && (key0_ < 784); \
      float4 b4_ = make_float4(0.f, 0.f, 0.f, 0.f); \
      if (ok_) b4_ = *(const float4*)(bias + (long)(qbase + qrow_) * 784 + key0_); \
      float p0_ = ok_ ? __expf(s_[0] * 0.125f + b4_.x) : 0.f; \
      float p1_ = ok_ ? __expf(s_[1] * 0.125f + b4_.y) : 0.f; \
      float p2_ = ok_ ? __expf(s_[2] * 0.125f + b4_.z) : 0.f; \
      float p3_ = ok_ ? __expf(s_[3] * 0.125f + b4_.w) : 0.f; \
      lpart[i_] += (p0_ + p1_) + (p2_ + p3_); \
      union { ushort4 u; __hip_bfloat16 hh[4]; } pk_; \
      pk_.hh[0] = __float2bfloat16(p0_); pk_.hh[1] = __float2bfloat16(p1_); \
      pk_.hh[2] = __float2bfloat16(p2_); pk_.hh[3] = __float2bfloat16(p3_); \
      *(ushort4*)((char*)&pPs[qrow_][0] + SWZB(qrow_, snt * 32 + kg * 8)) = pk_.u; \
    } \
    __syncthreads(); \
    _Pragma("unroll") \
    for (int mt_ = 0; mt_ < 7; ++mt_) { \
      const int prow_ = mt_ * 16 + cl; \
      bf16x8 pa0_ = *(const bf16x8*)((const char*)&pPs[prow_][0] + SWZB(prow_, kg * 16)); \
      bf16x8 pa1_ = *(const bf16x8*)((const char*)&pPs[prow_][0] + SWZB(prow_, 64 + kg * 16)); \
      acc[mt_][0] = mfma16(pa0_, VC0, acc[mt_][0]); \
      acc[mt_][0] = mfma16(pa1_, VC1, acc[mt_][0]); \
      acc[mt_][1] = mfma16(pa0_, VC2, acc[mt_][1]); \
      acc[mt_][1] = mfma16(pa1_, VC3, acc[mt_][1]); \
    } \
    __syncthreads(); }

__global__ __launch_bounds__(512, 6) void attn_mfma(
    const unsigned short* __restrict__ kbuf, const unsigned short* __restrict__ vt,
    const unsigned short* __restrict__ qn, const float* __restrict__ bias,
    unsigned short* __restrict__ O) {
  // XCD pair-swizzle decode
  const int p = blockIdx.x + 2 * (blockIdx.y + 12 * blockIdx.z);
  const int wrk = (p < 384) ? (p << 1) : (((p - 384) << 1) | 1);
  const int qt = wrk & 1;
  const int hb = wrk >> 1;
  const int h = hb % 12, b = hb / 12;

  const int tid = threadIdx.x;
  const int w = tid >> 6;
  const int lane = tid & 63;
  const int cl = lane & 15;
  const int kg = lane >> 4;
  const int kb = kg * 8;
  const int qbase = qt * 112;
  const int valid = 196 - qbase > 112 ? 112 : 196 - qbase;
  const int bh = b * 12 + h;

  __shared__ __align__(16) short Qs[112][72];
  __shared__ __align__(16) short Ks[2][64][72];
  __shared__ __align__(16) short pPs[112][72];
  __shared__ float pred[4][112];
  __shared__ float lsum[112];

  const bf16x8 zero8 = {0,0,0,0,0,0,0,0};
  const f32x4 zerof = {0.f,0.f,0.f,0.f};

  // stage Q (invalid rows zero), swizzled
  for (int f = tid; f < 896; f += 512) {
    int row = f >> 3, d8 = f & 7;
    bf16x8 v = zero8;
    if (row < valid)
      v = *(const bf16x8*)(qn + (long)(b * 196 + qbase + row) * 768 + h * 64 + d8 * 8);
    *(bf16x8*)((char*)&Qs[row][0] + SWZB(row, d8 * 16)) = v;
  }
  // stage K tile 0, swizzled
  {
    int kk = tid >> 3, d8 = tid & 7;
    bf16x8 v = *(const bf16x8*)(kbuf + ((long)b * 784 + kk) * 768 + h * 64 + d8 * 8);
    *(bf16x8*)((char*)&Ks[0][kk][0] + SWZB(kk, d8 * 16)) = v;
  }

  const int mt0 = w >> 2, snt = w & 3;
  const long vr0 = ((long)bh * 256 + w * 32 + cl) * 784;
  const long vr1 = vr0 + (long)16 * 784;

  // prefetch V tile 0 while barrier settles
  bf16x8 vA0, vA1, vA2, vA3;
  bf16x8 vB0 = zero8, vB1 = zero8, vB2 = zero8, vB3 = zero8;
  LOAD_VF(0, vA0, vA1, vA2, vA3);
  __syncthreads();

  f32x4 acc[7][2];
  #pragma unroll
  for (int mt = 0; mt < 7; ++mt) { acc[mt][0] = zerof; acc[mt][1] = zerof; }
  float lpart[4] = {0.f, 0.f, 0.f, 0.f};

  for (int kt2 = 0; kt2 < 13; kt2 += 2) {
    ATTN_STEP(kt2, 0, 1, vA0, vA1, vA2, vA3, vB0, vB1, vB2, vB3);
    if (kt2 + 1 < 13) {
      ATTN_STEP(kt2 + 1, 1, 0, vB0, vB1, vB2, vB3, vA0, vA1, vA2, vA3);
    }
  }

  // lsum: reduce lane partials over kg, then across the 4 snt waves
  #pragma unroll
  for (int i = 0; i < 4; ++i) {
    int mt = mt0 + 2 * i;
    if (mt >= 7) break;
    float v = lpart[i];
    v += __shfl_xor(v, 16);
    v += __shfl_xor(v, 32);
    if (kg == 0) pred[snt][mt * 16 + cl] = v;
  }
  __syncthreads();
  if (tid < 112)
    lsum[tid] = (pred[0][tid] + pred[1][tid]) + (pred[2][tid] + pred[3][tid]);
  __syncthreads();

  // store O = hswish(acc / lsum)
  #pragma unroll
  for (int mt = 0; mt < 7; ++mt) {
    #pragma unroll
    for (int r = 0; r < 4; ++r) {
      const int rl = mt * 16 + kg * 4 + r;
      if (rl < valid) {
        const float inv = 1.0f / lsum[rl];
        #pragma unroll
        for (int nt2 = 0; nt2 < 2; ++nt2) {
          float ov = hswish(acc[mt][nt2][r] * inv);
          __hip_bfloat16 hv = __float2bfloat16(ov);
          O[(long)(b * 196 + qbase + rl) * 3072 + h * 256 + w * 32 + nt2 * 16 + cl] =
              *(unsigned short*)&hv;
        }
      }
    }
  }
}

// ---------------------------------------------------------------------------
extern "C" void kernel_launch(void* const* d_in, const int* in_sizes, int n_in,
                              void* d_out, int out_size, void* d_ws, size_t ws_size,
                              hipStream_t stream) {
  if (ws_size < WS_TOTAL) return;

  const float* x    = (const float*)d_in[0];
  const float* Wqkv = (const float*)d_in[1];
  const float* bn1s = (const float*)d_in[2];
  const float* Wq   = (const float*)d_in[3];
  const float* bn2s = (const float*)d_in[4];
  const float* bias = (const float*)d_in[5];
  const float* Wout = (const float*)d_in[6];

  char* ws = (char*)d_ws;
  unsigned short* kb   = (unsigned short*)(ws + OFF_K);
  unsigned short* xbT  = (unsigned short*)(ws + OFF_XBT);
  unsigned short* xqT  = (unsigned short*)(ws + OFF_XQT);
  float* t1            = (float*)(ws + OFF_T1);
  float* t2            = (float*)(ws + OFF_T2);
  unsigned short* sxb1 = (unsigned short*)(ws + OFF_SXB1);
  unsigned short* sxb2 = (unsigned short*)(ws + OFF_SXB2);
  unsigned short* vtb  = (unsigned short*)(ws + OFF_VT);
  unsigned short* qnb  = (unsigned short*)(ws + OFF_QN);
  unsigned short* xb   = (unsigned short*)(ws + OFF_XB);
  unsigned short* Ob   = (unsigned short*)(ws + OFF_O);
  unsigned short* wqkvt= (unsigned short*)(ws + OFF_WQKVT);
  unsigned short* wqt  = (unsigned short*)(ws + OFF_WQT);
  unsigned short* woutt= (unsigned short*)(ws + OFF_WOUTT);
  float* ps1  = (float*)(ws + OFF_PS1);
  float* ps2  = (float*)(ws + OFF_PS2);
  float* sx1  = (float*)(ws + OFF_SX1);
  float* cs1  = (float*)(ws + OFF_CS1);
  float* sx2  = (float*)(ws + OFF_SX2);
  float* cs2  = (float*)(ws + OFF_CS2);
  float* a1w  = (float*)(ws + OFF_A1);
  float* b1w  = (float*)(ws + OFF_B1);
  float* a2w  = (float*)(ws + OFF_A2);
  float* b2w  = (float*)(ws + OFF_B2);
  float* out  = (float*)d_out;

  // prep: bf16 copies / transposes of x
  convert_bf16<<<dim3(4704), 256, 0, stream>>>(x, xb, (long)M1 * Kc / 8);
  transpose_bf16<<<dim3(12, 784), 256, 0, stream>>>(x, xbT, M1, Kc);
  transpose_gather_bf16<<<dim3(12, 196), 256, 0, stream>>>(x, xqT);
  rowsum_bf16<<<dim3(384), 256, 0, stream>>>(xbT, cs1, M1);
  rowsum_bf16<<<dim3(384), 256, 0, stream>>>(xqT, cs2, M2);

  // Sx via split-K MFMA
  sx_mfma<<<dim3(3, 3, CH1), 256, 0, stream>>>(xbT, ps1, M1, M1 / CH1);
  sx_mfma<<<dim3(3, 3, CH2), 256, 0, stream>>>(xqT, ps2, M2, M2 / CH2);
  reduce_chunks<<<dim3(576), 256, 0, stream>>>(ps1, sx1, 384 * 384, CH1);
  reduce_chunks<<<dim3(576), 256, 0, stream>>>(ps2, sx2, 384 * 384, CH2);
  convert_bf16<<<dim3(72), 256, 0, stream>>>(sx1, sxb1, 384 * 384 / 8);
  convert_bf16<<<dim3(72), 256, 0, stream>>>(sx2, sxb2, 384 * 384 / 8);

  // weight transposes (overwrite ps1 region - dead after reduce)
  transpose_bf16<<<dim3(120, 12), 256, 0, stream>>>(Wqkv, wqkvt, Kc, N1);
  transpose_bf16<<<dim3(24, 12),  256, 0, stream>>>(Wq,   wqt,   Kc, Dq);
  transpose_bf16<<<dim3(16, 96),  256, 0, stream>>>(Wout, woutt, 4 * Dq, OUTD);

  // BN coefficients: T = Sx @ W via MFMA, then column reduce
  gemm_mfma<0, 0><<<dim3(30, 3), 256, 0, stream>>>(sxb1, wqkvt, t1, nullptr, nullptr, N1, Kc);
  gemm_mfma<0, 0><<<dim3(6, 3),  256, 0, stream>>>(sxb2, wqt,   t2, nullptr, nullptr, Dq, Kc);
  bnfinal<<<dim3(60), 256, 0, stream>>>(Wqkv, t1, cs1, bn1s, a1w, b1w, N1, 1.f / (float)M1);
  bnfinal<<<dim3(12), 256, 0, stream>>>(Wq,   t2, cs2, bn2s, a2w, b2w, Dq, 1.f / (float)M2);

  // projections (Kbuf overwrites xbT/xqT/t1/t2/sxb - all dead)
  gemm_mfma<0, 1><<<dim3(6, 196), 256, 0, stream>>>(xb, wqkvt, kb, a1w, b1w, 768, Kc);
  gemm_mfma<0, 2><<<dim3(24, 196), 256, 0, stream>>>(
      xb, wqkvt + (long)768 * Kc, vtb, a1w + 768, b1w + 768, 3072, Kc);
  gemm_mfma<1, 1><<<dim3(6, 49), 256, 0, stream>>>(xb, wqt, qnb, a2w, b2w, Dq, Kc);

  // attention -> hswish(O)
  attn_mfma<<<dim3(2, 12, 32), 512, 0, stream>>>(kb, vtb, qnb, bias, Ob);

  // out = O @ Wout^T
  gemm_mfma<0, 0><<<dim3(4, 49), 256, 0, stream>>>(Ob, woutt, out, nullptr, nullptr, OUTD, 4 * Dq);
}

// Round 8
// 509.609 us; speedup vs baseline: 1.7320x; 1.7320x over previous
//
#include <hip/hip_runtime.h>
#include <hip/hip_bf16.h>

// ---------------------------------------------------------------------------
// LeViT subsample attention (round 7 = round 6 pipeline + round 5 attn).
//   1. prep: x -> xb (bf16), xbT (bf16 transposed), xqT (gathered transposed)
//   2. Sx = xbT @ xbT^T via split-K MFMA; cs = rowsum
//   3. T = Sx @ W (MFMA); bnfinal -> analytic BN coefficients a,b
//   4. Kbuf = BN(x@Wk); Vt = BN(x@Wv) transposed; Qn (gathered rows)
//   5. attn_mfma (round-5 proven): single-pass no-max softmax, V from global
//   6. out = O @ Wout^T -> f32
// ---------------------------------------------------------------------------

static constexpr int M1 = 25088, N1 = 3840, Kc = 384;
static constexpr int M2 = 6272, Dq = 768, OUTD = 512;
static constexpr int CH1 = 14, CH2 = 7;

static constexpr size_t OFF_K    = 0;            // bf16 25088x768 (late)
static constexpr size_t OFF_XBT  = 0;            // bf16 384x25088 (early)
static constexpr size_t OFF_XQT  = 19267584;     // bf16 384x6272
static constexpr size_t OFF_T1   = 24084480;     // f32 384x3840
static constexpr size_t OFF_T2   = 29982720;     // f32 384x768
static constexpr size_t OFF_SXB1 = 31162368;     // bf16 384x384
static constexpr size_t OFF_SXB2 = 31457280;     // ends 31752192 < OFF_VT
static constexpr size_t OFF_VT   = 38535168;     // bf16 (32*12*256)x784
static constexpr size_t OFF_QN   = 192675840;    // bf16 6272x768
static constexpr size_t OFF_O    = 202309632;    // bf16 6272x3072 (xb early)
static constexpr size_t OFF_XB   = OFF_O;
static constexpr size_t OFF_PS1  = 240844800;    // f32 14x384x384 (early)
static constexpr size_t OFF_WQKVT= 240844800;    // bf16 3840x384 (over PS1)
static constexpr size_t OFF_WQT  = 243793920;    // bf16 768x384
static constexpr size_t OFF_WOUTT= 244383744;    // bf16 512x3072
static constexpr size_t OFF_PS2  = 249123840;    // f32 7x384x384
static constexpr size_t OFF_SX1  = 253263360;
static constexpr size_t OFF_CS1  = 253853184;
static constexpr size_t OFF_SX2  = 253854720;
static constexpr size_t OFF_CS2  = 254444544;
static constexpr size_t OFF_A1   = 254446080;
static constexpr size_t OFF_B1   = 254461440;
static constexpr size_t OFF_A2   = 254476800;
static constexpr size_t OFF_B2   = 254479872;
static constexpr size_t WS_TOTAL = 254482944;

typedef __attribute__((ext_vector_type(8))) short bf16x8;
typedef __attribute__((ext_vector_type(4))) float f32x4;

static __device__ __forceinline__ f32x4 mfma16(bf16x8 a, bf16x8 b, f32x4 c) {
  return __builtin_amdgcn_mfma_f32_16x16x32_bf16(a, b, c, 0, 0, 0);
}

__device__ __forceinline__ void gload_lds16(const void* g, void* l) {
  __builtin_amdgcn_global_load_lds(
      (const __attribute__((address_space(1))) unsigned int*)g,
      (__attribute__((address_space(3))) unsigned int*)l, 16, 0, 0);
}

__device__ __forceinline__ float hswish(float x) {
  float t = fminf(fmaxf(x + 3.0f, 0.0f), 6.0f);
  return x * t * (1.0f / 6.0f);
}

// --------------------------- prep kernels ----------------------------------
__global__ __launch_bounds__(256) void convert_bf16(
    const float* __restrict__ in, unsigned short* __restrict__ out, long n8) {
  long i = (long)blockIdx.x * 256 + threadIdx.x;
  if (i >= n8) return;
  float4 a = ((const float4*)in)[i * 2];
  float4 b = ((const float4*)in)[i * 2 + 1];
  union { uint4 u; __hip_bfloat16 h[8]; } pk;
  pk.h[0] = __float2bfloat16(a.x); pk.h[1] = __float2bfloat16(a.y);
  pk.h[2] = __float2bfloat16(a.z); pk.h[3] = __float2bfloat16(a.w);
  pk.h[4] = __float2bfloat16(b.x); pk.h[5] = __float2bfloat16(b.y);
  pk.h[6] = __float2bfloat16(b.z); pk.h[7] = __float2bfloat16(b.w);
  ((uint4*)out)[i] = pk.u;
}

// in[R][C] f32 -> out[C][R] bf16; grid (C/32, R/32)
__global__ __launch_bounds__(256) void transpose_bf16(
    const float* __restrict__ in, unsigned short* __restrict__ out, int R, int C) {
  __shared__ float t[32][33];
  const int c0 = blockIdx.x * 32, r0 = blockIdx.y * 32;
  const int x = threadIdx.x & 31, y = threadIdx.x >> 5;
  #pragma unroll
  for (int i = y; i < 32; i += 8) t[i][x] = in[(long)(r0 + i) * C + c0 + x];
  __syncthreads();
  #pragma unroll
  for (int i = y; i < 32; i += 8) {
    __hip_bfloat16 v = __float2bfloat16(t[x][i]);
    out[(long)(c0 + i) * R + r0 + x] = *(unsigned short*)&v;
  }
}

// x (::2,::2 gathered rows) -> xqT[384][6272] bf16; grid (12, 196)
__global__ __launch_bounds__(256) void transpose_gather_bf16(
    const float* __restrict__ in, unsigned short* __restrict__ out) {
  __shared__ float t[32][33];
  const int c0 = blockIdx.x * 32, r0 = blockIdx.y * 32;
  const int x = threadIdx.x & 31, y = threadIdx.x >> 5;
  #pragma unroll
  for (int i = y; i < 32; i += 8) {
    int m2 = r0 + i;
    int bb = m2 / 196, tt = m2 - bb * 196;
    int h2 = tt / 14, w2 = tt - h2 * 14;
    long grow = (long)(bb * 784 + h2 * 56 + w2 * 2);
    t[i][x] = in[grow * 384 + c0 + x];
  }
  __syncthreads();
  #pragma unroll
  for (int i = y; i < 32; i += 8) {
    __hip_bfloat16 v = __float2bfloat16(t[x][i]);
    out[(long)(c0 + i) * 6272 + r0 + x] = *(unsigned short*)&v;
  }
}

// per-row sum of bf16 matrix row (grid = nrows)
__global__ __launch_bounds__(256) void rowsum_bf16(
    const unsigned short* __restrict__ src, float* __restrict__ dst, int ncols) {
  const long base = (long)blockIdx.x * ncols;
  float s = 0.f;
  for (int c = threadIdx.x * 8; c < ncols; c += 2048) {
    bf16x8 v = *(const bf16x8*)(src + base + c);
    #pragma unroll
    for (int j = 0; j < 8; ++j)
      s += __uint_as_float(((unsigned)(unsigned short)v[j]) << 16);
  }
  __shared__ float red[256];
  red[threadIdx.x] = s;
  __syncthreads();
  for (int st = 128; st > 0; st >>= 1) {
    if (threadIdx.x < st) red[threadIdx.x] += red[threadIdx.x + st];
    __syncthreads();
  }
  if (threadIdx.x == 0) dst[blockIdx.x] = red[0];
}

__global__ __launch_bounds__(256) void reduce_chunks(
    const float* __restrict__ src, float* __restrict__ dst, int nelem, int nchunks) {
  int i = blockIdx.x * 256 + threadIdx.x;
  if (i >= nelem) return;
  float s = 0.f;
  for (int c = 0; c < nchunks; ++c) s += src[(long)c * nelem + i];
  dst[i] = s;
}

// --------------------------- BN finalize -----------------------------------
__global__ __launch_bounds__(256) void bnfinal(
    const float* __restrict__ W, const float* __restrict__ T, const float* __restrict__ cs,
    const float* __restrict__ scale, float* __restrict__ a, float* __restrict__ b,
    int N, float invM) {
  const int j = blockIdx.x * 64 + (threadIdx.x & 63);
  const int rq = threadIdx.x >> 6;
  float yy = 0.f, mu = 0.f;
  for (int k = rq * 96; k < rq * 96 + 96; ++k) {
    float w = W[(long)k * N + j];
    yy += w * T[(long)k * N + j];
    mu += cs[k] * w;
  }
  __shared__ float r1[256], r2[256];
  r1[threadIdx.x] = yy; r2[threadIdx.x] = mu;
  __syncthreads();
  if (threadIdx.x < 64) {
    int t = threadIdx.x;
    yy = r1[t] + r1[t + 64] + r1[t + 128] + r1[t + 192];
    mu = r2[t] + r2[t + 64] + r2[t + 128] + r2[t + 192];
    float mean = mu * invM;
    float var = yy * invM - mean * mean;
    float ai = rsqrtf(var + 1e-5f) * scale[j];
    a[j] = ai;
    b[j] = -mean * ai;
  }
}

// ---------------------------------------------------------------------------
// split-K MFMA X @ X^T: Cpart[z] = X[:, zK..zK+Kchunk] times itself^T.
// X is [384][Kfull] bf16. grid (3, 3, chunks).
// ---------------------------------------------------------------------------
__global__ __launch_bounds__(256) void sx_mfma(
    const unsigned short* __restrict__ X, float* __restrict__ Cpart,
    int Kfull, int Kchunk) {
  __shared__ __align__(16) char As[16384];
  __shared__ __align__(16) char Bs[16384];
  const int tid = threadIdx.x;
  const int lane = tid & 63;
  const int wv = tid >> 6;
  const int wm = (wv >> 1) * 64, wn = (wv & 1) * 64;
  const int m0 = blockIdx.y * 128, n0 = blockIdx.x * 128;
  const int cl = lane & 15, kg = lane >> 4;
  const int srow = tid >> 3;
  const int swz = ((tid & 7) * 16) ^ ((srow & 7) << 4);
  const int ldsb = wv * 1024;
  const long zbase = (long)blockIdx.z * Kchunk;

  long arow[4], brow[4];
  #pragma unroll
  for (int is = 0; is < 4; ++is) {
    arow[is] = (long)(m0 + is * 32 + srow) * Kfull + zbase;
    brow[is] = (long)(n0 + is * 32 + srow) * Kfull + zbase;
  }

  f32x4 acc[4][4];
  const f32x4 zf = {0.f, 0.f, 0.f, 0.f};
  #pragma unroll
  for (int i = 0; i < 4; ++i)
    #pragma unroll
    for (int j = 0; j < 4; ++j) acc[i][j] = zf;

  for (int k0 = 0; k0 < Kchunk; k0 += 64) {
    #pragma unroll
    for (int is = 0; is < 4; ++is) {
      gload_lds16((const char*)X + (arow[is] + k0) * 2 + swz, As + is * 4096 + ldsb);
      gload_lds16((const char*)X + (brow[is] + k0) * 2 + swz, Bs + is * 4096 + ldsb);
    }
    __syncthreads();
    bf16x8 afr[4][2], bfr[4][2];
    #pragma unroll
    for (int t = 0; t < 4; ++t) {
      const int ar = wm + t * 16 + cl;
      const int br = wn + t * 16 + cl;
      const int sa = (ar & 7) << 4, sb = (br & 7) << 4;
      afr[t][0] = *(const bf16x8*)(As + ar * 128 + ((kg * 16) ^ sa));
      afr[t][1] = *(const bf16x8*)(As + ar * 128 + ((64 + kg * 16) ^ sa));
      bfr[t][0] = *(const bf16x8*)(Bs + br * 128 + ((kg * 16) ^ sb));
      bfr[t][1] = *(const bf16x8*)(Bs + br * 128 + ((64 + kg * 16) ^ sb));
    }
    #pragma unroll
    for (int mt = 0; mt < 4; ++mt)
      #pragma unroll
      for (int nt = 0; nt < 4; ++nt) {
        acc[mt][nt] = mfma16(bfr[nt][0], afr[mt][0], acc[mt][nt]);
        acc[mt][nt] = mfma16(bfr[nt][1], afr[mt][1], acc[mt][nt]);
      }
    __syncthreads();
  }

  float* Cp = Cpart + (long)blockIdx.z * 384 * 384;
  #pragma unroll
  for (int mt = 0; mt < 4; ++mt) {
    const int gm = m0 + wm + mt * 16 + cl;
    #pragma unroll
    for (int nt = 0; nt < 4; ++nt) {
      const int gn = n0 + wn + nt * 16 + kg * 4;
      *(float4*)(Cp + (long)gm * 384 + gn) =
          make_float4(acc[mt][nt][0], acc[mt][nt][1], acc[mt][nt][2], acc[mt][nt][3]);
    }
  }
}

// ---------------------------------------------------------------------------
// bf16 MFMA GEMM: C = A[M,K] @ Bt[N,K]^T.
// ---------------------------------------------------------------------------
template<int AMODE, int EPI>
__global__ __launch_bounds__(256) void gemm_mfma(
    const unsigned short* __restrict__ A, const unsigned short* __restrict__ Bt,
    void* __restrict__ Cout, const float* __restrict__ ea, const float* __restrict__ eb,
    int N, int K) {
  __shared__ __align__(16) char As[16384];
  __shared__ __align__(16) char Bs[16384];
  const int tid = threadIdx.x;
  const int lane = tid & 63;
  const int wv = tid >> 6;
  const int wm = (wv >> 1) * 64, wn = (wv & 1) * 64;
  const int m0 = blockIdx.y * 128, n0 = blockIdx.x * 128;
  const int cl = lane & 15, kg = lane >> 4;

  const int srow = tid >> 3;
  const int swz = ((tid & 7) * 16) ^ ((srow & 7) << 4);
  const int ldsb = wv * 1024;

  long arow[4], brow[4];
  #pragma unroll
  for (int is = 0; is < 4; ++is) {
    int gm = m0 + is * 32 + srow;
    long grow;
    if constexpr (AMODE == 1) {
      int bb = gm / 196, t = gm - bb * 196;
      int h2 = t / 14, w2 = t - h2 * 14;
      grow = (long)(bb * 784 + h2 * 56 + w2 * 2);
    } else {
      grow = gm;
    }
    arow[is] = grow * (long)K;
    brow[is] = (long)(n0 + is * 32 + srow) * (long)K;
  }

  f32x4 acc[4][4];
  const f32x4 zf = {0.f, 0.f, 0.f, 0.f};
  #pragma unroll
  for (int i = 0; i < 4; ++i)
    #pragma unroll
    for (int j = 0; j < 4; ++j) acc[i][j] = zf;

  for (int k0 = 0; k0 < K; k0 += 64) {
    #pragma unroll
    for (int is = 0; is < 4; ++is) {
      gload_lds16((const char*)A  + (arow[is] + k0) * 2 + swz, As + is * 4096 + ldsb);
      gload_lds16((const char*)Bt + (brow[is] + k0) * 2 + swz, Bs + is * 4096 + ldsb);
    }
    __syncthreads();
    bf16x8 afr[4][2], bfr[4][2];
    #pragma unroll
    for (int t = 0; t < 4; ++t) {
      const int ar = wm + t * 16 + cl;
      const int br = wn + t * 16 + cl;
      const int sa = (ar & 7) << 4, sb = (br & 7) << 4;
      afr[t][0] = *(const bf16x8*)(As + ar * 128 + ((kg * 16) ^ sa));
      afr[t][1] = *(const bf16x8*)(As + ar * 128 + ((64 + kg * 16) ^ sa));
      bfr[t][0] = *(const bf16x8*)(Bs + br * 128 + ((kg * 16) ^ sb));
      bfr[t][1] = *(const bf16x8*)(Bs + br * 128 + ((64 + kg * 16) ^ sb));
    }
    #pragma unroll
    for (int mt = 0; mt < 4; ++mt)
      #pragma unroll
      for (int nt = 0; nt < 4; ++nt) {
        if constexpr (EPI == 2) {
          acc[mt][nt] = mfma16(afr[mt][0], bfr[nt][0], acc[mt][nt]);
          acc[mt][nt] = mfma16(afr[mt][1], bfr[nt][1], acc[mt][nt]);
        } else {
          acc[mt][nt] = mfma16(bfr[nt][0], afr[mt][0], acc[mt][nt]);
          acc[mt][nt] = mfma16(bfr[nt][1], afr[mt][1], acc[mt][nt]);
        }
      }
    __syncthreads();
  }

  #pragma unroll
  for (int mt = 0; mt < 4; ++mt) {
    #pragma unroll
    for (int nt = 0; nt < 4; ++nt) {
      if constexpr (EPI == 2) {
        const int gm0 = m0 + wm + mt * 16 + kg * 4;
        const int gn = n0 + wn + nt * 16 + cl;
        const int bb = gm0 / 784, kk = gm0 - bb * 784;
        const int hh = gn >> 8, dvl = gn & 255;
        const float av = ea[gn], bv = eb[gn];
        union { ushort4 u; __hip_bfloat16 h[4]; } pk;
        pk.h[0] = __float2bfloat16(acc[mt][nt][0] * av + bv);
        pk.h[1] = __float2bfloat16(acc[mt][nt][1] * av + bv);
        pk.h[2] = __float2bfloat16(acc[mt][nt][2] * av + bv);
        pk.h[3] = __float2bfloat16(acc[mt][nt][3] * av + bv);
        *(ushort4*)((unsigned short*)Cout +
                    ((long)(bb * 12 + hh) * 256 + dvl) * 784 + kk) = pk.u;
      } else {
        const int gm = m0 + wm + mt * 16 + cl;
        const int gn = n0 + wn + nt * 16 + kg * 4;
        if constexpr (EPI == 1) {
          float4 a4 = *(const float4*)(ea + gn);
          float4 b4 = *(const float4*)(eb + gn);
          union { ushort4 u; __hip_bfloat16 h[4]; } pk;
          pk.h[0] = __float2bfloat16(acc[mt][nt][0] * a4.x + b4.x);
          pk.h[1] = __float2bfloat16(acc[mt][nt][1] * a4.y + b4.y);
          pk.h[2] = __float2bfloat16(acc[mt][nt][2] * a4.z + b4.z);
          pk.h[3] = __float2bfloat16(acc[mt][nt][3] * a4.w + b4.w);
          *(ushort4*)((unsigned short*)Cout + (long)gm * N + gn) = pk.u;
        } else {
          *(float4*)((float*)Cout + (long)gm * N + gn) =
              make_float4(acc[mt][nt][0], acc[mt][nt][1], acc[mt][nt][2], acc[mt][nt][3]);
        }
      }
    }
  }
}

// ---------------------------------------------------------------------------
// Single-pass MFMA flash attention (round-5 proven version, 155 us).
// ---------------------------------------------------------------------------
__global__ __launch_bounds__(512, 4) void attn_mfma(
    const unsigned short* __restrict__ kbuf, const unsigned short* __restrict__ vt,
    const unsigned short* __restrict__ qn, const float* __restrict__ bias,
    unsigned short* __restrict__ O) {
  const int qt = blockIdx.x, h = blockIdx.y, b = blockIdx.z;
  const int tid = threadIdx.x;
  const int w = tid >> 6;
  const int lane = tid & 63;
  const int cl = lane & 15;
  const int kg = lane >> 4;
  const int qbase = qt * 112;
  const int valid = 196 - qbase > 112 ? 112 : 196 - qbase;
  const int bh = b * 12 + h;

  __shared__ __align__(16) short Qs[112][72];
  __shared__ __align__(16) short Ks[2][64][72];
  __shared__ __align__(16) short pPs[112][72];
  __shared__ float pred[4][112];
  __shared__ float lsum[112];

  const bf16x8 zero8 = {0,0,0,0,0,0,0,0};
  const f32x4 zerof = {0.f,0.f,0.f,0.f};

  for (int f = tid; f < 896; f += 512) {
    int row = f >> 3, d8 = f & 7;
    bf16x8 v = zero8;
    if (row < valid)
      v = *(const bf16x8*)(qn + (long)(b * 196 + qbase + row) * 768 + h * 64 + d8 * 8);
    *(bf16x8*)&Qs[row][d8 * 8] = v;
  }
  {
    int kk = tid >> 3, d8 = tid & 7;
    bf16x8 v = *(const bf16x8*)(kbuf + ((long)b * 784 + kk) * 768 + h * 64 + d8 * 8);
    *(bf16x8*)&Ks[0][kk][d8 * 8] = v;
  }
  __syncthreads();

  const int mt0 = w >> 2, snt = w & 3;
  const int kb = kg * 8;

  f32x4 acc[7][2];
  #pragma unroll
  for (int mt = 0; mt < 7; ++mt) { acc[mt][0] = zerof; acc[mt][1] = zerof; }
  float lpart[4] = {0.f, 0.f, 0.f, 0.f};

  for (int kt = 0; kt < 13; ++kt) {
    const int k0 = kt * 64;
    const int cur = kt & 1;
    if (kt < 12) {
      int kk = tid >> 3, d8 = tid & 7;
      bf16x8 v = zero8;
      if (k0 + 64 + kk < 784)
        v = *(const bf16x8*)(kbuf + ((long)b * 784 + k0 + 64 + kk) * 768 + h * 64 + d8 * 8);
      *(bf16x8*)&Ks[cur ^ 1][kk][d8 * 8] = v;
    }
    bf16x8 vf00, vf01, vf10, vf11;
    {
      const long vrow0 = ((long)bh * 256 + w * 32 + cl) * 784;
      const long vrow1 = ((long)bh * 256 + w * 32 + 16 + cl) * 784;
      vf00 = *(const bf16x8*)(vt + vrow0 + k0 + kb);
      vf10 = *(const bf16x8*)(vt + vrow0 + k0 + 32 + kb);
      vf01 = *(const bf16x8*)(vt + vrow1 + k0 + kb);
      vf11 = *(const bf16x8*)(vt + vrow1 + k0 + 32 + kb);
    }
    #pragma unroll
    for (int i = 0; i < 4; ++i) {
      int mt = mt0 + 2 * i;
      if (mt >= 7) break;
      bf16x8 q0 = *(const bf16x8*)&Qs[mt * 16 + cl][kb];
      bf16x8 q1 = *(const bf16x8*)&Qs[mt * 16 + cl][32 + kb];
      bf16x8 kk0 = *(const bf16x8*)&Ks[cur][snt * 16 + cl][kb];
      bf16x8 kk1 = *(const bf16x8*)&Ks[cur][snt * 16 + cl][32 + kb];
      f32x4 s = mfma16(kk1, q1, mfma16(kk0, q0, zerof));
      const int rowl = mt * 16 + cl;
      const int key0 = k0 + snt * 16 + kg * 4;
      const bool ok = (rowl < valid) && (key0 < 784);
      float4 b4 = make_float4(0.f, 0.f, 0.f, 0.f);
      if (ok) b4 = *(const float4*)(bias + (long)(qbase + rowl) * 784 + key0);
      float p0 = ok ? __expf(s[0] * 0.125f + b4.x) : 0.f;
      float p1 = ok ? __expf(s[1] * 0.125f + b4.y) : 0.f;
      float p2 = ok ? __expf(s[2] * 0.125f + b4.z) : 0.f;
      float p3 = ok ? __expf(s[3] * 0.125f + b4.w) : 0.f;
      lpart[i] += (p0 + p1) + (p2 + p3);
      union { ushort4 u; __hip_bfloat16 hh[4]; } pk;
      pk.hh[0] = __float2bfloat16(p0);
      pk.hh[1] = __float2bfloat16(p1);
      pk.hh[2] = __float2bfloat16(p2);
      pk.hh[3] = __float2bfloat16(p3);
      *(ushort4*)&pPs[rowl][snt * 16 + kg * 4] = pk.u;
    }
    __syncthreads();
    #pragma unroll
    for (int mt = 0; mt < 7; ++mt) {
      bf16x8 pa0 = *(const bf16x8*)&pPs[mt * 16 + cl][kb];
      bf16x8 pa1 = *(const bf16x8*)&pPs[mt * 16 + cl][32 + kb];
      acc[mt][0] = mfma16(pa0, vf00, acc[mt][0]);
      acc[mt][0] = mfma16(pa1, vf10, acc[mt][0]);
      acc[mt][1] = mfma16(pa0, vf01, acc[mt][1]);
      acc[mt][1] = mfma16(pa1, vf11, acc[mt][1]);
    }
    __syncthreads();
  }

  #pragma unroll
  for (int i = 0; i < 4; ++i) {
    int mt = mt0 + 2 * i;
    if (mt >= 7) break;
    float v = lpart[i];
    v += __shfl_xor(v, 16);
    v += __shfl_xor(v, 32);
    if (kg == 0) pred[snt][mt * 16 + cl] = v;
  }
  __syncthreads();
  if (tid < 112)
    lsum[tid] = (pred[0][tid] + pred[1][tid]) + (pred[2][tid] + pred[3][tid]);
  __syncthreads();

  #pragma unroll
  for (int mt = 0; mt < 7; ++mt) {
    #pragma unroll
    for (int r = 0; r < 4; ++r) {
      const int rl = mt * 16 + kg * 4 + r;
      if (rl < valid) {
        const float inv = 1.0f / lsum[rl];
        #pragma unroll
        for (int nt2 = 0; nt2 < 2; ++nt2) {
          float ov = hswish(acc[mt][nt2][r] * inv);
          __hip_bfloat16 hv = __float2bfloat16(ov);
          O[(long)(b * 196 + qbase + rl) * 3072 + h * 256 + w * 32 + nt2 * 16 + cl] =
              *(unsigned short*)&hv;
        }
      }
    }
  }
}

// ---------------------------------------------------------------------------
extern "C" void kernel_launch(void* const* d_in, const int* in_sizes, int n_in,
                              void* d_out, int out_size, void* d_ws, size_t ws_size,
                              hipStream_t stream) {
  if (ws_size < WS_TOTAL) return;

  const float* x    = (const float*)d_in[0];
  const float* Wqkv = (const float*)d_in[1];
  const float* bn1s = (const float*)d_in[2];
  const float* Wq   = (const float*)d_in[3];
  const float* bn2s = (const float*)d_in[4];
  const float* bias = (const float*)d_in[5];
  const float* Wout = (const float*)d_in[6];

  char* ws = (char*)d_ws;
  unsigned short* kb   = (unsigned short*)(ws + OFF_K);
  unsigned short* xbT  = (unsigned short*)(ws + OFF_XBT);
  unsigned short* xqT  = (unsigned short*)(ws + OFF_XQT);
  float* t1            = (float*)(ws + OFF_T1);
  float* t2            = (float*)(ws + OFF_T2);
  unsigned short* sxb1 = (unsigned short*)(ws + OFF_SXB1);
  unsigned short* sxb2 = (unsigned short*)(ws + OFF_SXB2);
  unsigned short* vtb  = (unsigned short*)(ws + OFF_VT);
  unsigned short* qnb  = (unsigned short*)(ws + OFF_QN);
  unsigned short* xb   = (unsigned short*)(ws + OFF_XB);
  unsigned short* Ob   = (unsigned short*)(ws + OFF_O);
  unsigned short* wqkvt= (unsigned short*)(ws + OFF_WQKVT);
  unsigned short* wqt  = (unsigned short*)(ws + OFF_WQT);
  unsigned short* woutt= (unsigned short*)(ws + OFF_WOUTT);
  float* ps1  = (float*)(ws + OFF_PS1);
  float* ps2  = (float*)(ws + OFF_PS2);
  float* sx1  = (float*)(ws + OFF_SX1);
  float* cs1  = (float*)(ws + OFF_CS1);
  float* sx2  = (float*)(ws + OFF_SX2);
  float* cs2  = (float*)(ws + OFF_CS2);
  float* a1w  = (float*)(ws + OFF_A1);
  float* b1w  = (float*)(ws + OFF_B1);
  float* a2w  = (float*)(ws + OFF_A2);
  float* b2w  = (float*)(ws + OFF_B2);
  float* out  = (float*)d_out;

  // prep: bf16 copies / transposes of x
  convert_bf16<<<dim3(4704), 256, 0, stream>>>(x, xb, (long)M1 * Kc / 8);
  transpose_bf16<<<dim3(12, 784), 256, 0, stream>>>(x, xbT, M1, Kc);
  transpose_gather_bf16<<<dim3(12, 196), 256, 0, stream>>>(x, xqT);
  rowsum_bf16<<<dim3(384), 256, 0, stream>>>(xbT, cs1, M1);
  rowsum_bf16<<<dim3(384), 256, 0, stream>>>(xqT, cs2, M2);

  // Sx via split-K MFMA
  sx_mfma<<<dim3(3, 3, CH1), 256, 0, stream>>>(xbT, ps1, M1, M1 / CH1);
  sx_mfma<<<dim3(3, 3, CH2), 256, 0, stream>>>(xqT, ps2, M2, M2 / CH2);
  reduce_chunks<<<dim3(576), 256, 0, stream>>>(ps1, sx1, 384 * 384, CH1);
  reduce_chunks<<<dim3(576), 256, 0, stream>>>(ps2, sx2, 384 * 384, CH2);
  convert_bf16<<<dim3(72), 256, 0, stream>>>(sx1, sxb1, 384 * 384 / 8);
  convert_bf16<<<dim3(72), 256, 0, stream>>>(sx2, sxb2, 384 * 384 / 8);

  // weight transposes (overwrite ps1 region - dead after reduce)
  transpose_bf16<<<dim3(120, 12), 256, 0, stream>>>(Wqkv, wqkvt, Kc, N1);
  transpose_bf16<<<dim3(24, 12),  256, 0, stream>>>(Wq,   wqt,   Kc, Dq);
  transpose_bf16<<<dim3(16, 96),  256, 0, stream>>>(Wout, woutt, 4 * Dq, OUTD);

  // BN coefficients: T = Sx @ W via MFMA, then column reduce
  gemm_mfma<0, 0><<<dim3(30, 3), 256, 0, stream>>>(sxb1, wqkvt, t1, nullptr, nullptr, N1, Kc);
  gemm_mfma<0, 0><<<dim3(6, 3),  256, 0, stream>>>(sxb2, wqt,   t2, nullptr, nullptr, Dq, Kc);
  bnfinal<<<dim3(60), 256, 0, stream>>>(Wqkv, t1, cs1, bn1s, a1w, b1w, N1, 1.f / (float)M1);
  bnfinal<<<dim3(12), 256, 0, stream>>>(Wq,   t2, cs2, bn2s, a2w, b2w, Dq, 1.f / (float)M2);

  // projections (Kbuf overwrites xbT/xqT/t1/t2/sxb - all dead)
  gemm_mfma<0, 1><<<dim3(6, 196), 256, 0, stream>>>(xb, wqkvt, kb, a1w, b1w, 768, Kc);
  gemm_mfma<0, 2><<<dim3(24, 196), 256, 0, stream>>>(
      xb, wqkvt + (long)768 * Kc, vtb, a1w + 768, b1w + 768, 3072, Kc);
  gemm_mfma<1, 1><<<dim3(6, 49), 256, 0, stream>>>(xb, wqt, qnb, a2w, b2w, Dq, Kc);

  // attention -> hswish(O)
  attn_mfma<<<dim3(2, 12, 32), 512, 0, stream>>>(kb, vtb, qnb, bias, Ob);

  // out = O @ Wout^T
  gemm_mfma<0, 0><<<dim3(4, 49), 256, 0, stream>>>(Ob, woutt, out, nullptr, nullptr, OUTD, 4 * Dq);
}